// Round 12
// baseline (108.211 us; speedup 1.0000x reference)
//
#include <hip/hip_runtime.h>

#define B_ 8
#define C_ 3
#define R_ 8
#define H_ 512
#define W_ 512
#define HW_ (H_*W_)
#define S_ 1024
#define CB_ 25
#define TB_ 10

// output offsets (floats)
#define O_AREA 0
#define O_BBOX 8192
#define O_COLOR 40960
#define O_TEX 655360
#define O_GRADS 2621440
#define OUT_TOT 15204352

// roles (R11 champion), but hist blocks dispersed at bid%5==2
#define NBBOX 8
#define NTEX (B_*C_*R_)        // 192
#define NCOL (B_*C_)           // 24
#define NHIST (NBBOX + NTEX + NCOL)   // 224
#define NCONV 1024
#define NGRID (NHIST + NCONV)  // 1248
#define HIST_SPAN (NHIST * 5)  // 1120: hist bids are 2,7,...,1117

// packed-u16 label scratch: 2,097,152 u16 = 4 MB
#define PK_WORDS 1048576
#define NEED_WS ((size_t)PK_WORDS * 4)
#define SCR_OFF (OUT_TOT - PK_WORDS)   // overlays grads planes bc>=22
#define CONV_SAFE (22 << 18)
#define CONV_ALL  (24 << 18)

// ---------------- K0: pack labels int32 -> u16 ----------------
__global__ __launch_bounds__(1024) void k_pack(const int* __restrict__ lab,
                                               unsigned* __restrict__ plab) {
  const int i = blockIdx.x * 1024 + threadIdx.x;
  const int4 a = ((const int4*)lab)[2 * i];
  const int4 b = ((const int4*)lab)[2 * i + 1];
  uint4 o;
  o.x = (unsigned)(a.x) | ((unsigned)a.y << 16);
  o.y = (unsigned)(a.z) | ((unsigned)a.w << 16);
  o.z = (unsigned)(b.x) | ((unsigned)b.y << 16);
  o.w = (unsigned)(b.z) | ((unsigned)b.w << 16);
  ((uint4*)plab)[i] = o;
}

// ---------------- K1: fused, hist dispersed ----------------
__global__ __launch_bounds__(1024) void k_fused(
    const float* __restrict__ img,
    const int* __restrict__ imgs_bins,
    const int* __restrict__ grads_bins,
    const unsigned* __restrict__ plab,
    float* __restrict__ out,
    int convHi) {
  __shared__ unsigned smem[12800];   // 51.2 KB union
  const int bid = blockIdx.x;
  const int tid = threadIdx.x;

  const bool is_hist = (bid < HIST_SPAN) && (bid % 5 == 2);
  if (!is_hist) {
    // ---------- Scharr gradients, grid-stride over dense conv index ----------
    const int nh_before = (bid < HIST_SPAN) ? ((bid + 2) / 5) : NHIST;
    const int cb = bid - nh_before;          // 0..1023
    for (int i = cb * 1024 + tid; i < convHi; i += NCONV * 1024) {
      const int pix = i & (HW_ - 1);
      const int bc = i >> 18;
      const int x = pix & (W_ - 1);
      const int y = pix >> 9;
      const float* im = img + (size_t)bc * HW_;
      const bool xm = x > 0, xp = x < W_ - 1, ym = y > 0, yp = y < H_ - 1;
      const float i00 = (ym && xm) ? im[pix - W_ - 1] : 0.f;
      const float i01 = ym ? im[pix - W_] : 0.f;
      const float i02 = (ym && xp) ? im[pix - W_ + 1] : 0.f;
      const float i10 = xm ? im[pix - 1] : 0.f;
      const float i12 = xp ? im[pix + 1] : 0.f;
      const float i20 = (yp && xm) ? im[pix + W_ - 1] : 0.f;
      const float i21 = yp ? im[pix + W_] : 0.f;
      const float i22 = (yp && xp) ? im[pix + W_ + 1] : 0.f;
      const float gx = 3.f*(i02 - i00) + 10.f*(i12 - i10) + 3.f*(i22 - i20);
      const float gy = 3.f*(i20 - i00) + 10.f*(i21 - i01) + 3.f*(i22 - i02);
      out[O_GRADS + (size_t)(bc*2 + 0)*HW_ + pix] = gx;
      out[O_GRADS + (size_t)(bc*2 + 1)*HW_ + pix] = gy;
    }
    return;
  }

  const int hid = bid / 5;   // 0..223
  if (hid < NBBOX) {
    // ---------- bbox for image b ----------
    const int b = hid;
    int* mn = (int*)smem;
    mn[tid] = W_; mn[S_ + tid] = H_; mn[2*S_ + tid] = 0; mn[3*S_ + tid] = 0;
    __syncthreads();
    const uint4* lp = (const uint4*)(plab + (size_t)b * (HW_/2));
    for (int t = tid; t < HW_/8; t += 1024) {
      const uint4 L = lp[t];
      const int p = t * 8;
      const int y = p >> 9;
      const int x = p & (W_ - 1);
      #define BBX(l, xx) { const int ll = (int)(l); \
        atomicMin(&mn[ll], xx);        atomicMin(&mn[S_ + ll], y); \
        atomicMax(&mn[2*S_ + ll], xx); atomicMax(&mn[3*S_ + ll], y); }
      BBX(L.x & 0xFFFFu, x)     BBX(L.x >> 16, x + 1)
      BBX(L.y & 0xFFFFu, x + 2) BBX(L.y >> 16, x + 3)
      BBX(L.z & 0xFFFFu, x + 4) BBX(L.z >> 16, x + 5)
      BBX(L.w & 0xFFFFu, x + 6) BBX(L.w >> 16, x + 7)
      #undef BBX
    }
    __syncthreads();
    {
      const int xmn = mn[tid], ymn = mn[S_ + tid];
      const int xmx = mn[2*S_ + tid], ymx = mn[3*S_ + tid];
      float4 v;
      v.x = (float)xmn; v.y = (float)ymn;
      v.z = (float)(xmx - xmn); v.w = (float)(ymx - ymn);
      ((float4*)(out + O_BBOX))[b * S_ + tid] = v;
    }
  } else if (hid < NBBOX + NTEX) {
    // ---------- texture hist plane ----------
    const int plane = hid - NBBOX;          // b*24 + cr
    const int b = plane / (C_*R_);
    const int cr = plane - b * (C_*R_);
    int* h = (int*)smem;
    for (int i = tid; i < S_*TB_; i += 1024) h[i] = 0;
    __syncthreads();
    const int4* bp = (const int4*)(grads_bins + (size_t)plane * HW_);
    const uint4* lp = (const uint4*)(plab + (size_t)b * (HW_/2));
    for (int t = tid; t < HW_/8; t += 1024) {
      const uint4 L = lp[t];
      const int4 b0 = bp[2*t];
      const int4 b1 = bp[2*t + 1];
      atomicAdd(&h[(int)(L.x & 0xFFFFu)*TB_ + b0.x], 1);
      atomicAdd(&h[(int)(L.x >> 16)*TB_ + b0.y], 1);
      atomicAdd(&h[(int)(L.y & 0xFFFFu)*TB_ + b0.z], 1);
      atomicAdd(&h[(int)(L.y >> 16)*TB_ + b0.w], 1);
      atomicAdd(&h[(int)(L.z & 0xFFFFu)*TB_ + b1.x], 1);
      atomicAdd(&h[(int)(L.z >> 16)*TB_ + b1.y], 1);
      atomicAdd(&h[(int)(L.w & 0xFFFFu)*TB_ + b1.z], 1);
      atomicAdd(&h[(int)(L.w >> 16)*TB_ + b1.w], 1);
    }
    __syncthreads();
    {
      const int base = tid * TB_;
      int s = 0;
      #pragma unroll
      for (int t = 0; t < TB_; ++t) s += h[base + t];
      const float inv = 1.0f / ((float)s * 24.0f + 1e-12f);
      float* o = out + O_TEX + (size_t)b * (S_ * 240) + tid * 240 + cr * TB_;
      #pragma unroll
      for (int t = 0; t < TB_; ++t) o[t] = (float)h[base + t] * inv;
      if (cr == 0) out[O_AREA + b * S_ + tid] = (float)s;
    }
  } else {
    // ---------- color hist plane ----------
    const int plane = hid - NBBOX - NTEX;   // b*3 + c
    const int b = plane / C_;
    const int c = plane - b * C_;
    unsigned* h = smem;
    for (int i = tid; i < (S_*CB_)/2; i += 1024) h[i] = 0;
    __syncthreads();
    const int4* bp = (const int4*)(imgs_bins + (size_t)plane * HW_);
    const uint4* lp = (const uint4*)(plab + (size_t)b * (HW_/2));
    for (int t = tid; t < HW_/8; t += 1024) {
      const uint4 L = lp[t];
      const int4 b0 = bp[2*t];
      const int4 b1 = bp[2*t + 1];
      #define CADD(l, bin) { const int j = (int)(l)*CB_ + (bin); \
        atomicAdd(&h[j >> 1], 1u << ((j & 1) << 4)); }
      CADD(L.x & 0xFFFFu, b0.x) CADD(L.x >> 16, b0.y)
      CADD(L.y & 0xFFFFu, b0.z) CADD(L.y >> 16, b0.w)
      CADD(L.z & 0xFFFFu, b1.x) CADD(L.z >> 16, b1.y)
      CADD(L.w & 0xFFFFu, b1.z) CADD(L.w >> 16, b1.w)
      #undef CADD
    }
    __syncthreads();
    {
      int s = 0;
      #pragma unroll
      for (int ci = 0; ci < CB_; ++ci) {
        const int j = tid * CB_ + ci;
        s += (int)((h[j >> 1] >> ((j & 1) << 4)) & 0xFFFFu);
      }
      const float inv = 1.0f / ((float)s * 3.0f + 1e-12f);
      float* o = out + O_COLOR + (size_t)b * (S_ * 75) + tid * 75 + c * CB_;
      #pragma unroll
      for (int ci = 0; ci < CB_; ++ci) {
        const int j = tid * CB_ + ci;
        o[ci] = (float)((h[j >> 1] >> ((j & 1) << 4)) & 0xFFFFu) * inv;
      }
    }
  }
}

// ---------------- K2 (fallback only): conv tail bc 22..23 ----------------
__global__ __launch_bounds__(1024) void k_conv_tail(const float* __restrict__ img,
                                                    float* __restrict__ out) {
  const int i = CONV_SAFE + blockIdx.x * 1024 + threadIdx.x;
  const int pix = i & (HW_ - 1);
  const int bc = i >> 18;
  const int x = pix & (W_ - 1);
  const int y = pix >> 9;
  const float* im = img + (size_t)bc * HW_;
  const bool xm = x > 0, xp = x < W_ - 1, ym = y > 0, yp = y < H_ - 1;
  const float i00 = (ym && xm) ? im[pix - W_ - 1] : 0.f;
  const float i01 = ym ? im[pix - W_] : 0.f;
  const float i02 = (ym && xp) ? im[pix - W_ + 1] : 0.f;
  const float i10 = xm ? im[pix - 1] : 0.f;
  const float i12 = xp ? im[pix + 1] : 0.f;
  const float i20 = (yp && xm) ? im[pix + W_ - 1] : 0.f;
  const float i21 = yp ? im[pix + W_] : 0.f;
  const float i22 = (yp && xp) ? im[pix + W_ + 1] : 0.f;
  const float gx = 3.f*(i02 - i00) + 10.f*(i12 - i10) + 3.f*(i22 - i20);
  const float gy = 3.f*(i20 - i00) + 10.f*(i21 - i01) + 3.f*(i22 - i02);
  out[O_GRADS + (size_t)(bc*2 + 0)*HW_ + pix] = gx;
  out[O_GRADS + (size_t)(bc*2 + 1)*HW_ + pix] = gy;
}

extern "C" void kernel_launch(void* const* d_in, const int* in_sizes, int n_in,
                              void* d_out, int out_size, void* d_ws, size_t ws_size,
                              hipStream_t stream) {
  const float* img = (const float*)d_in[0];
  const int* imgs_bins = (const int*)d_in[1];
  const int* grads_bins = (const int*)d_in[2];
  const int* reg_lab = (const int*)d_in[3];
  float* out = (float*)d_out;

  const bool ws_ok = ws_size >= NEED_WS;
  unsigned* plab = ws_ok ? (unsigned*)d_ws : (unsigned*)(out + SCR_OFF);
  const int convHi = ws_ok ? CONV_ALL : CONV_SAFE;

  hipLaunchKernelGGL(k_pack, dim3(256), dim3(1024), 0, stream, reg_lab, plab);
  hipLaunchKernelGGL(k_fused, dim3(NGRID), dim3(1024), 0, stream,
                     img, imgs_bins, grads_bins, plab, out, convHi);
  if (!ws_ok) {
    hipLaunchKernelGGL(k_conv_tail, dim3(512), dim3(1024), 0, stream, img, out);
  }
}

// Round 13
// 90.032 us; speedup vs baseline: 1.2019x; 1.2019x over previous
//
#include <hip/hip_runtime.h>

#define B_ 8
#define C_ 3
#define R_ 8
#define H_ 512
#define W_ 512
#define HW_ (H_*W_)
#define S_ 1024
#define CB_ 25
#define TB_ 10

// output offsets (floats)
#define O_AREA 0
#define O_BBOX 8192
#define O_COLOR 40960
#define O_TEX 655360
#define O_GRADS 2621440
#define OUT_TOT 15204352

// hist kernel roles
#define NBBOX 8
#define NTEX (B_*C_*R_)        // 192
#define NCOL (B_*C_)           // 24
#define NHIST (NBBOX + NTEX + NCOL)   // 224

#define NCONV 1024

// packed-u16 label scratch: 4 MB
#define PK_WORDS 1048576
#define NEED_WS ((size_t)PK_WORDS * 4)
#define SCR_OFF (OUT_TOT - PK_WORDS)   // overlays grads tail; consumed before conv runs

// ---------------- K0: pack labels int32 -> u16 ----------------
__global__ __launch_bounds__(1024) void k_pack(const int* __restrict__ lab,
                                               unsigned* __restrict__ plab) {
  const int i = blockIdx.x * 1024 + threadIdx.x;
  const int4 a = ((const int4*)lab)[2 * i];
  const int4 b = ((const int4*)lab)[2 * i + 1];
  uint4 o;
  o.x = (unsigned)(a.x) | ((unsigned)a.y << 16);
  o.y = (unsigned)(a.z) | ((unsigned)a.w << 16);
  o.z = (unsigned)(b.x) | ((unsigned)b.y << 16);
  o.w = (unsigned)(b.z) | ((unsigned)b.w << 16);
  ((uint4*)plab)[i] = o;
}

// ---------------- K1: hist-only (bbox / tex / col), 224 blocks ----------------
__global__ __launch_bounds__(1024) void k_hist(
    const int* __restrict__ imgs_bins,
    const int* __restrict__ grads_bins,
    const unsigned* __restrict__ plab,
    float* __restrict__ out) {
  __shared__ unsigned smem[12800];   // 51.2 KB union
  const int bid = blockIdx.x;
  const int tid = threadIdx.x;

  if (bid < NBBOX) {
    // ---------- bbox for image b ----------
    const int b = bid;
    int* mn = (int*)smem;
    mn[tid] = W_; mn[S_ + tid] = H_; mn[2*S_ + tid] = 0; mn[3*S_ + tid] = 0;
    __syncthreads();
    const uint4* lp = (const uint4*)(plab + (size_t)b * (HW_/2));
    for (int t = tid; t < HW_/8; t += 1024) {
      const uint4 L = lp[t];
      const int p = t * 8;
      const int y = p >> 9;
      const int x = p & (W_ - 1);
      #define BBX(l, xx) { const int ll = (int)(l); \
        atomicMin(&mn[ll], xx);        atomicMin(&mn[S_ + ll], y); \
        atomicMax(&mn[2*S_ + ll], xx); atomicMax(&mn[3*S_ + ll], y); }
      BBX(L.x & 0xFFFFu, x)     BBX(L.x >> 16, x + 1)
      BBX(L.y & 0xFFFFu, x + 2) BBX(L.y >> 16, x + 3)
      BBX(L.z & 0xFFFFu, x + 4) BBX(L.z >> 16, x + 5)
      BBX(L.w & 0xFFFFu, x + 6) BBX(L.w >> 16, x + 7)
      #undef BBX
    }
    __syncthreads();
    {
      const int xmn = mn[tid], ymn = mn[S_ + tid];
      const int xmx = mn[2*S_ + tid], ymx = mn[3*S_ + tid];
      float4 v;
      v.x = (float)xmn; v.y = (float)ymn;
      v.z = (float)(xmx - xmn); v.w = (float)(ymx - ymn);
      ((float4*)(out + O_BBOX))[b * S_ + tid] = v;
    }
  } else if (bid < NBBOX + NTEX) {
    // ---------- texture hist plane (b, cr) ----------
    const int plane = bid - NBBOX;          // b*24 + cr
    const int b = plane / (C_*R_);
    const int cr = plane - b * (C_*R_);
    int* h = (int*)smem;                    // 10240 ints
    for (int i = tid; i < S_*TB_; i += 1024) h[i] = 0;
    __syncthreads();
    const int4* bp = (const int4*)(grads_bins + (size_t)plane * HW_);
    const uint4* lp = (const uint4*)(plab + (size_t)b * (HW_/2));
    for (int t = tid; t < HW_/8; t += 1024) {
      const uint4 L = lp[t];
      const int4 b0 = bp[2*t];
      const int4 b1 = bp[2*t + 1];
      atomicAdd(&h[(int)(L.x & 0xFFFFu)*TB_ + b0.x], 1);
      atomicAdd(&h[(int)(L.x >> 16)*TB_ + b0.y], 1);
      atomicAdd(&h[(int)(L.y & 0xFFFFu)*TB_ + b0.z], 1);
      atomicAdd(&h[(int)(L.y >> 16)*TB_ + b0.w], 1);
      atomicAdd(&h[(int)(L.z & 0xFFFFu)*TB_ + b1.x], 1);
      atomicAdd(&h[(int)(L.z >> 16)*TB_ + b1.y], 1);
      atomicAdd(&h[(int)(L.w & 0xFFFFu)*TB_ + b1.z], 1);
      atomicAdd(&h[(int)(L.w >> 16)*TB_ + b1.w], 1);
    }
    __syncthreads();
    {
      const int base = tid * TB_;
      int s = 0;
      #pragma unroll
      for (int t = 0; t < TB_; ++t) s += h[base + t];
      const float inv = 1.0f / ((float)s * 24.0f + 1e-12f);
      float* o = out + O_TEX + (size_t)b * (S_ * 240) + tid * 240 + cr * TB_;
      #pragma unroll
      for (int t = 0; t < TB_; ++t) o[t] = (float)h[base + t] * inv;
      if (cr == 0) out[O_AREA + b * S_ + tid] = (float)s;
    }
  } else {
    // ---------- color hist plane (b,c) ----------
    const int plane = bid - NBBOX - NTEX;   // b*3 + c
    const int b = plane / C_;
    const int c = plane - b * C_;
    unsigned* h = smem;
    for (int i = tid; i < (S_*CB_)/2; i += 1024) h[i] = 0;
    __syncthreads();
    const int4* bp = (const int4*)(imgs_bins + (size_t)plane * HW_);
    const uint4* lp = (const uint4*)(plab + (size_t)b * (HW_/2));
    for (int t = tid; t < HW_/8; t += 1024) {
      const uint4 L = lp[t];
      const int4 b0 = bp[2*t];
      const int4 b1 = bp[2*t + 1];
      #define CADD(l, bin) { const int j = (int)(l)*CB_ + (bin); \
        atomicAdd(&h[j >> 1], 1u << ((j & 1) << 4)); }
      CADD(L.x & 0xFFFFu, b0.x) CADD(L.x >> 16, b0.y)
      CADD(L.y & 0xFFFFu, b0.z) CADD(L.y >> 16, b0.w)
      CADD(L.z & 0xFFFFu, b1.x) CADD(L.z >> 16, b1.y)
      CADD(L.w & 0xFFFFu, b1.z) CADD(L.w >> 16, b1.w)
      #undef CADD
    }
    __syncthreads();
    {
      int s = 0;
      #pragma unroll
      for (int ci = 0; ci < CB_; ++ci) {
        const int j = tid * CB_ + ci;
        s += (int)((h[j >> 1] >> ((j & 1) << 4)) & 0xFFFFu);
      }
      const float inv = 1.0f / ((float)s * 3.0f + 1e-12f);
      float* o = out + O_COLOR + (size_t)b * (S_ * 75) + tid * 75 + c * CB_;
      #pragma unroll
      for (int ci = 0; ci < CB_; ++ci) {
        const int j = tid * CB_ + ci;
        o[ci] = (float)((h[j >> 1] >> ((j & 1) << 4)) & 0xFFFFu) * inv;
      }
    }
  }
}

// ---------------- K2: conv-only (runs after hist; scratch already consumed) ----------------
__global__ __launch_bounds__(1024) void k_conv(const float* __restrict__ img,
                                               float* __restrict__ out) {
  const int tot = B_*C_*HW_;
  for (int i = blockIdx.x * 1024 + threadIdx.x; i < tot; i += NCONV * 1024) {
    const int pix = i & (HW_ - 1);
    const int bc = i >> 18;
    const int x = pix & (W_ - 1);
    const int y = pix >> 9;
    const float* im = img + (size_t)bc * HW_;
    const bool xm = x > 0, xp = x < W_ - 1, ym = y > 0, yp = y < H_ - 1;
    const float i00 = (ym && xm) ? im[pix - W_ - 1] : 0.f;
    const float i01 = ym ? im[pix - W_] : 0.f;
    const float i02 = (ym && xp) ? im[pix - W_ + 1] : 0.f;
    const float i10 = xm ? im[pix - 1] : 0.f;
    const float i12 = xp ? im[pix + 1] : 0.f;
    const float i20 = (yp && xm) ? im[pix + W_ - 1] : 0.f;
    const float i21 = yp ? im[pix + W_] : 0.f;
    const float i22 = (yp && xp) ? im[pix + W_ + 1] : 0.f;
    const float gx = 3.f*(i02 - i00) + 10.f*(i12 - i10) + 3.f*(i22 - i20);
    const float gy = 3.f*(i20 - i00) + 10.f*(i21 - i01) + 3.f*(i22 - i02);
    out[O_GRADS + (size_t)(bc*2 + 0)*HW_ + pix] = gx;
    out[O_GRADS + (size_t)(bc*2 + 1)*HW_ + pix] = gy;
  }
}

extern "C" void kernel_launch(void* const* d_in, const int* in_sizes, int n_in,
                              void* d_out, int out_size, void* d_ws, size_t ws_size,
                              hipStream_t stream) {
  const float* img = (const float*)d_in[0];
  const int* imgs_bins = (const int*)d_in[1];
  const int* grads_bins = (const int*)d_in[2];
  const int* reg_lab = (const int*)d_in[3];
  float* out = (float*)d_out;

  const bool ws_ok = ws_size >= NEED_WS;
  unsigned* plab = ws_ok ? (unsigned*)d_ws : (unsigned*)(out + SCR_OFF);

  hipLaunchKernelGGL(k_pack, dim3(256), dim3(1024), 0, stream, reg_lab, plab);
  hipLaunchKernelGGL(k_hist, dim3(NHIST), dim3(1024), 0, stream,
                     imgs_bins, grads_bins, plab, out);
  // conv runs after k_hist completes; it may freely overwrite the whole grads
  // region including the fallback scratch (already consumed).
  hipLaunchKernelGGL(k_conv, dim3(NCONV), dim3(1024), 0, stream, img, out);
}

// Round 14
// 79.503 us; speedup vs baseline: 1.3611x; 1.1324x over previous
//
#include <hip/hip_runtime.h>

#define B_ 8
#define C_ 3
#define R_ 8
#define H_ 512
#define W_ 512
#define HW_ (H_*W_)
#define S_ 1024
#define CB_ 25
#define TB_ 10

// output offsets (floats)
#define O_AREA 0
#define O_BBOX 8192
#define O_COLOR 40960
#define O_TEX 655360
#define O_GRADS 2621440
#define OUT_TOT 15204352

// block roles (R3 champion layout)
#define NBBOX 8
#define NTEX (B_*C_*R_)        // 192
#define NCOL (B_*C_)           // 24
#define NHIST (NBBOX + NTEX + NCOL)   // 224
#define NCONV 1024
#define NGRID (NHIST + NCONV)  // 1248

// packed-u16 label scratch: 2,097,152 u16 = 4 MB
#define PK_WORDS 1048576
#define NEED_WS ((size_t)PK_WORDS * 4)
#define SCR_OFF (OUT_TOT - PK_WORDS)   // overlays grads planes p>=44 (bc>=22)
#define CONV_SAFE (22 << 18)           // fused conv covers bc<22 in fallback
#define CONV_ALL  (24 << 18)

// ---------------- K0: pack labels int32 -> u16 (8 px / thread) ----------------
__global__ __launch_bounds__(1024) void k_pack(const int* __restrict__ lab,
                                               unsigned* __restrict__ plab) {
  const int i = blockIdx.x * 1024 + threadIdx.x;   // 262,144 threads
  const int4 a = ((const int4*)lab)[2 * i];
  const int4 b = ((const int4*)lab)[2 * i + 1];
  uint4 o;
  o.x = (unsigned)(a.x) | ((unsigned)a.y << 16);
  o.y = (unsigned)(a.z) | ((unsigned)a.w << 16);
  o.z = (unsigned)(b.x) | ((unsigned)b.y << 16);
  o.w = (unsigned)(b.z) | ((unsigned)b.w << 16);
  ((uint4*)plab)[i] = o;
}

// ---------------- K1: fused hist + bbox + conv (champion structure) ----------------
__global__ __launch_bounds__(1024) void k_fused(
    const float* __restrict__ img,
    const int* __restrict__ imgs_bins,
    const int* __restrict__ grads_bins,
    const unsigned* __restrict__ plab,   // packed u16 labels
    float* __restrict__ out,
    int convHi) {
  __shared__ unsigned smem[12800];   // 51.2 KB union
  const int bid = blockIdx.x;
  const int tid = threadIdx.x;

  if (bid < NBBOX) {
    // ---------- bbox for image b: LDS min/max, exclusive final write ----------
    const int b = bid;
    int* mn = (int*)smem;   // xmin[S], ymin[S], xmax[S], ymax[S]
    mn[tid] = W_; mn[S_ + tid] = H_; mn[2*S_ + tid] = 0; mn[3*S_ + tid] = 0;
    __syncthreads();
    const uint4* lp = (const uint4*)(plab + (size_t)b * (HW_/2));
    for (int t = tid; t < HW_/8; t += 1024) {
      const uint4 L = lp[t];
      const int p = t * 8;
      const int y = p >> 9;
      const int x = p & (W_ - 1);    // 8-aligned: x..x+7 same row
      #define BBX(l, xx) { const int ll = (int)(l); \
        atomicMin(&mn[ll], xx);        atomicMin(&mn[S_ + ll], y); \
        atomicMax(&mn[2*S_ + ll], xx); atomicMax(&mn[3*S_ + ll], y); }
      BBX(L.x & 0xFFFFu, x)     BBX(L.x >> 16, x + 1)
      BBX(L.y & 0xFFFFu, x + 2) BBX(L.y >> 16, x + 3)
      BBX(L.z & 0xFFFFu, x + 4) BBX(L.z >> 16, x + 5)
      BBX(L.w & 0xFFFFu, x + 6) BBX(L.w >> 16, x + 7)
      #undef BBX
    }
    __syncthreads();
    {
      const int xmn = mn[tid], ymn = mn[S_ + tid];
      const int xmx = mn[2*S_ + tid], ymx = mn[3*S_ + tid];
      float4 v;
      v.x = (float)xmn; v.y = (float)ymn;
      v.z = (float)(xmx - xmn); v.w = (float)(ymx - ymn);
      ((float4*)(out + O_BBOX))[b * S_ + tid] = v;
    }
  } else if (bid < NBBOX + NTEX) {
    // ---------- texture hist plane (b, cr): full image, final write ----------
    const int plane = bid - NBBOX;          // b*24 + cr
    const int b = plane / (C_*R_);
    const int cr = plane - b * (C_*R_);
    int* h = (int*)smem;                    // 10240 ints (40 KB)
    for (int i = tid; i < S_*TB_; i += 1024) h[i] = 0;
    __syncthreads();
    const int4* bp = (const int4*)(grads_bins + (size_t)plane * HW_);
    const uint4* lp = (const uint4*)(plab + (size_t)b * (HW_/2));
    for (int t = tid; t < HW_/8; t += 1024) {
      const uint4 L = lp[t];
      const int4 b0 = bp[2*t];
      const int4 b1 = bp[2*t + 1];
      atomicAdd(&h[(int)(L.x & 0xFFFFu)*TB_ + b0.x], 1);
      atomicAdd(&h[(int)(L.x >> 16)*TB_ + b0.y], 1);
      atomicAdd(&h[(int)(L.y & 0xFFFFu)*TB_ + b0.z], 1);
      atomicAdd(&h[(int)(L.y >> 16)*TB_ + b0.w], 1);
      atomicAdd(&h[(int)(L.z & 0xFFFFu)*TB_ + b1.x], 1);
      atomicAdd(&h[(int)(L.z >> 16)*TB_ + b1.y], 1);
      atomicAdd(&h[(int)(L.w & 0xFFFFu)*TB_ + b1.z], 1);
      atomicAdd(&h[(int)(L.w >> 16)*TB_ + b1.w], 1);
    }
    __syncthreads();
    {
      const int base = tid * TB_;
      int s = 0;
      #pragma unroll
      for (int t = 0; t < TB_; ++t) s += h[base + t];
      const float inv = 1.0f / ((float)s * 24.0f + 1e-12f);
      float* o = out + O_TEX + (size_t)b * (S_ * 240) + tid * 240 + cr * TB_;
      #pragma unroll
      for (int t = 0; t < TB_; ++t) o[t] = (float)h[base + t] * inv;
      if (cr == 0) out[O_AREA + b * S_ + tid] = (float)s;
    }
  } else if (bid < NHIST) {
    // ---------- color hist plane (b,c): u16-packed LDS, final write ----------
    const int plane = bid - NBBOX - NTEX;   // b*3 + c
    const int b = plane / C_;
    const int c = plane - b * C_;
    unsigned* h = smem;                     // 12800 words (51.2 KB)
    for (int i = tid; i < (S_*CB_)/2; i += 1024) h[i] = 0;
    __syncthreads();
    const int4* bp = (const int4*)(imgs_bins + (size_t)plane * HW_);
    const uint4* lp = (const uint4*)(plab + (size_t)b * (HW_/2));
    for (int t = tid; t < HW_/8; t += 1024) {
      const uint4 L = lp[t];
      const int4 b0 = bp[2*t];
      const int4 b1 = bp[2*t + 1];
      #define CADD(l, bin) { const int j = (int)(l)*CB_ + (bin); \
        atomicAdd(&h[j >> 1], 1u << ((j & 1) << 4)); }
      CADD(L.x & 0xFFFFu, b0.x) CADD(L.x >> 16, b0.y)
      CADD(L.y & 0xFFFFu, b0.z) CADD(L.y >> 16, b0.w)
      CADD(L.z & 0xFFFFu, b1.x) CADD(L.z >> 16, b1.y)
      CADD(L.w & 0xFFFFu, b1.z) CADD(L.w >> 16, b1.w)
      #undef CADD
    }
    __syncthreads();
    {
      int s = 0;
      #pragma unroll
      for (int ci = 0; ci < CB_; ++ci) {
        const int j = tid * CB_ + ci;
        s += (int)((h[j >> 1] >> ((j & 1) << 4)) & 0xFFFFu);
      }
      const float inv = 1.0f / ((float)s * 3.0f + 1e-12f);
      float* o = out + O_COLOR + (size_t)b * (S_ * 75) + tid * 75 + c * CB_;
      #pragma unroll
      for (int ci = 0; ci < CB_; ++ci) {
        const int j = tid * CB_ + ci;
        o[ci] = (float)((h[j >> 1] >> ((j & 1) << 4)) & 0xFFFFu) * inv;
      }
    }
  } else {
    // ---------- Scharr gradients, grid-stride ----------
    const int cb = bid - NHIST;
    for (int i = cb * 1024 + tid; i < convHi; i += NCONV * 1024) {
      const int pix = i & (HW_ - 1);
      const int bc = i >> 18;
      const int x = pix & (W_ - 1);
      const int y = pix >> 9;
      const float* im = img + (size_t)bc * HW_;
      const bool xm = x > 0, xp = x < W_ - 1, ym = y > 0, yp = y < H_ - 1;
      const float i00 = (ym && xm) ? im[pix - W_ - 1] : 0.f;
      const float i01 = ym ? im[pix - W_] : 0.f;
      const float i02 = (ym && xp) ? im[pix - W_ + 1] : 0.f;
      const float i10 = xm ? im[pix - 1] : 0.f;
      const float i12 = xp ? im[pix + 1] : 0.f;
      const float i20 = (yp && xm) ? im[pix + W_ - 1] : 0.f;
      const float i21 = yp ? im[pix + W_] : 0.f;
      const float i22 = (yp && xp) ? im[pix + W_ + 1] : 0.f;
      const float gx = 3.f*(i02 - i00) + 10.f*(i12 - i10) + 3.f*(i22 - i20);
      const float gy = 3.f*(i20 - i00) + 10.f*(i21 - i01) + 3.f*(i22 - i02);
      out[O_GRADS + (size_t)(bc*2 + 0)*HW_ + pix] = gx;
      out[O_GRADS + (size_t)(bc*2 + 1)*HW_ + pix] = gy;
    }
  }
}

// ---------------- K2 (fallback only): conv tail bc 22..23 ----------------
__global__ __launch_bounds__(1024) void k_conv_tail(const float* __restrict__ img,
                                                    float* __restrict__ out) {
  const int i = CONV_SAFE + blockIdx.x * 1024 + threadIdx.x;
  const int pix = i & (HW_ - 1);
  const int bc = i >> 18;
  const int x = pix & (W_ - 1);
  const int y = pix >> 9;
  const float* im = img + (size_t)bc * HW_;
  const bool xm = x > 0, xp = x < W_ - 1, ym = y > 0, yp = y < H_ - 1;
  const float i00 = (ym && xm) ? im[pix - W_ - 1] : 0.f;
  const float i01 = ym ? im[pix - W_] : 0.f;
  const float i02 = (ym && xp) ? im[pix - W_ + 1] : 0.f;
  const float i10 = xm ? im[pix - 1] : 0.f;
  const float i12 = xp ? im[pix + 1] : 0.f;
  const float i20 = (yp && xm) ? im[pix + W_ - 1] : 0.f;
  const float i21 = yp ? im[pix + W_] : 0.f;
  const float i22 = (yp && xp) ? im[pix + W_ + 1] : 0.f;
  const float gx = 3.f*(i02 - i00) + 10.f*(i12 - i10) + 3.f*(i22 - i20);
  const float gy = 3.f*(i20 - i00) + 10.f*(i21 - i01) + 3.f*(i22 - i02);
  out[O_GRADS + (size_t)(bc*2 + 0)*HW_ + pix] = gx;
  out[O_GRADS + (size_t)(bc*2 + 1)*HW_ + pix] = gy;
}

extern "C" void kernel_launch(void* const* d_in, const int* in_sizes, int n_in,
                              void* d_out, int out_size, void* d_ws, size_t ws_size,
                              hipStream_t stream) {
  const float* img = (const float*)d_in[0];
  const int* imgs_bins = (const int*)d_in[1];
  const int* grads_bins = (const int*)d_in[2];
  const int* reg_lab = (const int*)d_in[3];
  float* out = (float*)d_out;

  const bool ws_ok = ws_size >= NEED_WS;
  unsigned* plab = ws_ok ? (unsigned*)d_ws : (unsigned*)(out + SCR_OFF);
  const int convHi = ws_ok ? CONV_ALL : CONV_SAFE;

  hipLaunchKernelGGL(k_pack, dim3(256), dim3(1024), 0, stream, reg_lab, plab);
  hipLaunchKernelGGL(k_fused, dim3(NGRID), dim3(1024), 0, stream,
                     img, imgs_bins, grads_bins, plab, out, convHi);
  if (!ws_ok) {
    hipLaunchKernelGGL(k_conv_tail, dim3(512), dim3(1024), 0, stream, img, out);
  }
}